// Round 13
// baseline (119.881 us; speedup 1.0000x reference)
//
#include <hip/hip_runtime.h>
#include <stdint.h>

typedef __attribute__((ext_vector_type(4))) float f32x4;
typedef __attribute__((ext_vector_type(8))) short short8;

#define NROWS 8192

static __device__ __forceinline__ unsigned int f2bf(float f) {
  unsigned int u = __float_as_uint(f);
  return (u + 0x7fffu + ((u >> 16) & 1u)) >> 16;  // RNE
}
static __device__ __forceinline__ float bf2f(unsigned int h) {
  return __uint_as_float(h << 16);
}
static __device__ __forceinline__ float fast_exp2(float x) {
#if __has_builtin(__builtin_amdgcn_exp2f)
  return __builtin_amdgcn_exp2f(x);
#else
  float r;
  asm("v_exp_f32 %0, %1" : "=v"(r) : "v"(x));
  return r;
#endif
}

// hs layout: per 256B row r, 16B chunk c stored at chunk position c ^ (r&7).
// (Kept from the staged rounds; for direct global reads it just permutes
// which lane reads which chunk — swizzle folds to a per-lane constant since
// row & 7 == l16 & 7 for all fragment rows.)

// ---------------------------------------------------------------------------
// Kernel 1: projection fc2(elu(fc1(z))) + L2-normalize, bf16 MFMA + f32
// epilogue. Output rows pre-scaled by sqrt(2*log2 e) so Gram MFMA output is
// the exp2 argument, written in the swizzled global layout. (unchanged)
// ---------------------------------------------------------------------------
__global__ __launch_bounds__(256) void proj_kernel(
    const float* __restrict__ z1, const float* __restrict__ z2,
    const float* __restrict__ w1g, const float* __restrict__ b1g,
    const float* __restrict__ w2g, const float* __restrict__ b2g,
    unsigned short* __restrict__ hs1, unsigned short* __restrict__ hs2) {
  __shared__ unsigned short W1[128 * 128];
  __shared__ unsigned short W2[128 * 128];
  __shared__ unsigned short X[64 * 128];
  const int tid = threadIdx.x;
  const int w = tid >> 6, l = tid & 63, l16 = l & 15, lh = l >> 4;
  const int zi = blockIdx.x >> 7, rb = blockIdx.x & 127;
  const float* zg = (zi ? z2 : z1) + (size_t)rb * 64 * 128;
  unsigned short* outp = (zi ? hs2 : hs1) + (size_t)rb * 64 * 128;

  float bias1[8], bias2[8];
#pragma unroll
  for (int nf = 0; nf < 8; ++nf) {
    bias1[nf] = b1g[nf * 16 + l16];
    bias2[nf] = b2g[nf * 16 + l16];
  }

#pragma unroll
  for (int t = 0; t < 16; ++t) {
    int c = tid + t * 256;
    int r = c >> 5, q = c & 31;
    int off = r * 256 + ((((q >> 1) ^ (r & 7)) << 4) | ((q & 1) << 3));
    f32x4 va = *(const f32x4*)&w1g[c * 4];
    f32x4 vb = *(const f32x4*)&w2g[c * 4];
    uint2 pa, pb;
    pa.x = f2bf(va.x) | (f2bf(va.y) << 16);
    pa.y = f2bf(va.z) | (f2bf(va.w) << 16);
    pb.x = f2bf(vb.x) | (f2bf(vb.y) << 16);
    pb.y = f2bf(vb.z) | (f2bf(vb.w) << 16);
    *(uint2*)((char*)W1 + off) = pa;
    *(uint2*)((char*)W2 + off) = pb;
  }
#pragma unroll
  for (int t = 0; t < 8; ++t) {
    int c = tid + t * 256;
    int r = c >> 5, q = c & 31;
    int off = r * 256 + ((((q >> 1) ^ (r & 7)) << 4) | ((q & 1) << 3));
    f32x4 v = *(const f32x4*)&zg[c * 4];
    uint2 p;
    p.x = f2bf(v.x) | (f2bf(v.y) << 16);
    p.y = f2bf(v.z) | (f2bf(v.w) << 16);
    *(uint2*)((char*)X + off) = p;
  }
  __syncthreads();

  const f32x4 ZERO = {0.f, 0.f, 0.f, 0.f};
  const int arow = w * 16 + l16;

  short8 a1[4];
#pragma unroll
  for (int ks = 0; ks < 4; ++ks)
    a1[ks] = *(const short8*)((const char*)X + arow * 256 +
                              ((ks * 64 + lh * 16) ^ ((arow & 7) << 4)));
  f32x4 h[8];
#pragma unroll
  for (int nf = 0; nf < 8; ++nf) {
    const int brow = nf * 16 + l16;
    const char* bp = (const char*)W1 + brow * 256;
    f32x4 c = ZERO;
#pragma unroll
    for (int ks = 0; ks < 4; ++ks) {
      short8 b = *(const short8*)(bp + ((ks * 64 + lh * 16) ^ ((brow & 7) << 4)));
      c = __builtin_amdgcn_mfma_f32_16x16x32_bf16(a1[ks], b, c, 0, 0, 0);
    }
#pragma unroll
    for (int r = 0; r < 4; ++r) {
      float x = c[r] + bias1[nf];
      c[r] = x > 0.f ? x : expm1f(x);
    }
    h[nf] = c;
  }
  __syncthreads();

#pragma unroll
  for (int nf = 0; nf < 8; ++nf)
#pragma unroll
    for (int r = 0; r < 4; ++r) {
      int row = w * 16 + lh * 4 + r;
      int c2 = (nf * 16 + l16) * 2;
      int off = row * 256 + ((c2 & ~15) ^ ((row & 7) << 4)) + (c2 & 15);
      *(unsigned short*)((char*)X + off) = (unsigned short)f2bf(h[nf][r]);
    }
  __syncthreads();

  short8 a2[4];
#pragma unroll
  for (int ks = 0; ks < 4; ++ks)
    a2[ks] = *(const short8*)((const char*)X + arow * 256 +
                              ((ks * 64 + lh * 16) ^ ((arow & 7) << 4)));
  f32x4 o[8];
#pragma unroll
  for (int nf = 0; nf < 8; ++nf) {
    const int brow = nf * 16 + l16;
    const char* bp = (const char*)W2 + brow * 256;
    f32x4 c = ZERO;
#pragma unroll
    for (int ks = 0; ks < 4; ++ks) {
      short8 b = *(const short8*)(bp + ((ks * 64 + lh * 16) ^ ((brow & 7) << 4)));
      c = __builtin_amdgcn_mfma_f32_16x16x32_bf16(a2[ks], b, c, 0, 0, 0);
    }
#pragma unroll
    for (int r = 0; r < 4; ++r) c[r] += bias2[nf];
    o[nf] = c;
  }

  float ss[4] = {0.f, 0.f, 0.f, 0.f};
#pragma unroll
  for (int nf = 0; nf < 8; ++nf)
#pragma unroll
    for (int r = 0; r < 4; ++r) ss[r] += o[nf][r] * o[nf][r];
#pragma unroll
  for (int m = 1; m <= 8; m <<= 1)
#pragma unroll
    for (int r = 0; r < 4; ++r) ss[r] += __shfl_xor(ss[r], m, 64);
  float sc[4];
#pragma unroll
  for (int r = 0; r < 4; ++r)
    sc[r] = 1.6986436005760381f / fmaxf(sqrtf(ss[r]), 1e-12f);

#pragma unroll
  for (int nf = 0; nf < 8; ++nf)
#pragma unroll
    for (int r = 0; r < 4; ++r) {
      int row = w * 16 + lh * 4 + r;
      int c2 = (nf * 16 + l16) * 2;
      int off = row * 256 + ((c2 & ~15) ^ ((row & 7) << 4)) + (c2 & 15);
      *(unsigned short*)((char*)outp + off) = (unsigned short)f2bf(o[nf][r] * sc[r]);
    }
}

// ---------------------------------------------------------------------------
// Kernel 2: fused Gram + exp2 + row-sum (+ col-sum in pass 2).
// ROUND-13 CHANGE (Common-mistake #7): hs1+hs2 = 4MB = L2-resident, so DROP
// the LDS B-staging and ALL main-loop barriers. Each wave reads B fragments
// directly from global/L2 (all 4 waves of a block read identical addresses
// -> 3 of 4 hits served by L1), double-buffered in registers: bf[(nf+1)&1]
// is prefetched before group nf's MFMAs (static idx under unroll, rule #20).
// Swizzle folds to per-lane constants koff[ks] (row&7 == l16&7). r12's wall
// was 70us with MFMA 20us busy + VALU 25us busy + ~40us barrier-phase-locked
// stall; with no barriers the waves free-run against the vector-memory path.
// Pass 2 keeps the 2KB csbuf + one barrier/ct (block-uniform cond -> legal).
// Grid 1536 = 3 x 64 rowblocks(128) x 8 col-ranges(1024); 256 thr, af[2][4].
// ---------------------------------------------------------------------------
#define EXPBLOCK(G, SLOT)                                             \
  {                                                                   \
    float cs = 0.f;                                                   \
    _Pragma("unroll") for (int mf = 0; mf < 2; ++mf)                  \
        _Pragma("unroll") for (int r = 0; r < 4; ++r) {               \
      float e = fast_exp2(cbuf[SLOT][mf][r]);                         \
      rs[mf][r] += e;                                                 \
      if (do_cs) cs += e;                                             \
    }                                                                 \
    if (do_cs) {                                                      \
      cs += __shfl_xor(cs, 16, 64);                                   \
      cs += __shfl_xor(cs, 32, 64);                                   \
      if (lh == 0) csbuf[ct & 1][w][(G)*16 + l16] = cs;               \
    }                                                                 \
  }

#define LOADBF(P, G)                                                  \
  {                                                                   \
    const char* _bp = browbase + (size_t)(G) * 4096;                  \
    _Pragma("unroll") for (int ks = 0; ks < 4; ++ks)                  \
        bf[P][ks] = *(const short8*)(_bp + koff[ks]);                 \
  }

__global__ __launch_bounds__(256, 4) void gram_kernel(
    const unsigned short* __restrict__ hs1, const unsigned short* __restrict__ hs2,
    float* __restrict__ Rp,     // [24][8192] (pass*8+cr) row-sum partials
    float* __restrict__ R21p) { // [64][8192] col-sum partials (pass 2)
  __shared__ float csbuf[2][4][64];  // pass-2 col-sum exchange only (2KB)

  const int tid = threadIdx.x;
  const int w = tid >> 6, l = tid & 63, l16 = l & 15, lh = l >> 4;
  const int pass = blockIdx.x >> 9;
  const int idx = blockIdx.x & 511;
  const int rb = idx >> 3;  // 64 rowblocks of 128 rows
  const int cr = idx & 7;   // 8 col-ranges of 1024 cols

  const unsigned short* Ag = (pass == 1) ? hs2 : hs1;
  const unsigned short* Bg = (pass == 0) ? hs1 : hs2;
  const bool do_cs = (pass == 2);

  // per-lane constant 16B-chunk offsets within a 256B row (XOR swizzle folded:
  // fragment rows are nf*16+l16 or mf*16+l16 -> row&7 == l16&7 always)
  int koff[4];
#pragma unroll
  for (int ks = 0; ks < 4; ++ks)
    koff[ks] = (ks * 64 + lh * 16) ^ ((l16 & 7) << 4);

  short8 af[2][4];  // 32 rows per wave, resident
  {
    const char* abase = (const char*)Ag + ((size_t)rb * 128 + w * 32) * 256;
#pragma unroll
    for (int mf = 0; mf < 2; ++mf)
#pragma unroll
      for (int ks = 0; ks < 4; ++ks)
        af[mf][ks] = *(const short8*)(abase + (mf * 16 + l16) * 256 + koff[ks]);
  }

  float rs[2][4];
#pragma unroll
  for (int mf = 0; mf < 2; ++mf)
#pragma unroll
    for (int r = 0; r < 4; ++r) rs[mf][r] = 0.f;
  const f32x4 ZERO = {0.f, 0.f, 0.f, 0.f};

  // per-lane B row base: global col = cr*1024 + g*16 + l16, g = ct*4+nf
  const char* browbase = (const char*)Bg + ((size_t)cr * 1024 + l16) * 256;

  short8 bf[2][4];  // register double-buffer for B fragments
  LOADBF(0, 0)

  for (int ct = 0; ct < 16; ++ct) {
    if (do_cs) {
      __syncthreads();  // csbuf[(ct-1)&1] writes visible (pass-2 blocks only)
      if (w == 0 && ct > 0) {
        float v = (csbuf[(ct - 1) & 1][0][l] + csbuf[(ct - 1) & 1][1][l]) +
                  (csbuf[(ct - 1) & 1][2][l] + csbuf[(ct - 1) & 1][3][l]);
        R21p[(size_t)rb * NROWS + cr * 1024 + (ct - 1) * 64 + l] = v;
      }
    }
    f32x4 cbuf[2][2];
#pragma unroll
    for (int nf = 0; nf < 4; ++nf) {
      const int g = ct * 4 + nf;
      if (g + 1 < 64) LOADBF((nf + 1) & 1, g + 1)  // prefetch next group
#pragma unroll
      for (int mf = 0; mf < 2; ++mf) cbuf[nf & 1][mf] = ZERO;
      __builtin_amdgcn_s_setprio(1);
#pragma unroll
      for (int ks = 0; ks < 4; ++ks)
#pragma unroll
        for (int mf = 0; mf < 2; ++mf)
          cbuf[nf & 1][mf] = __builtin_amdgcn_mfma_f32_16x16x32_bf16(
              af[mf][ks], bf[nf & 1][ks], cbuf[nf & 1][mf], 0, 0, 0);
      __builtin_amdgcn_s_setprio(0);
      // deferred exp of PREVIOUS group (operands long ready; overlaps both
      // the prefetch latency and the MFMA pipe)
      if (nf > 0) EXPBLOCK(nf - 1, (nf ^ 1) & 1)
    }
    EXPBLOCK(3, 1)
  }
  if (do_cs) {
    __syncthreads();
    if (w == 0) {  // flush last tile (ct=15 -> slot 1)
      float v = (csbuf[1][0][l] + csbuf[1][1][l]) + (csbuf[1][2][l] + csbuf[1][3][l]);
      R21p[(size_t)rb * NROWS + cr * 1024 + 15 * 64 + l] = v;
    }
  }

  // row-sums: reduce over the 16 col-lanes; A-row = mf*16 + lh*4 + r [m89]
#pragma unroll
  for (int m = 1; m <= 8; m <<= 1)
#pragma unroll
    for (int mf = 0; mf < 2; ++mf)
#pragma unroll
      for (int r = 0; r < 4; ++r) rs[mf][r] += __shfl_xor(rs[mf][r], m, 64);
  if (l16 == 0) {
    float* base = &Rp[(size_t)(pass * 8 + cr) * NROWS + rb * 128 + w * 32];
#pragma unroll
    for (int mf = 0; mf < 2; ++mf) {
      f32x4 v = {rs[mf][0], rs[mf][1], rs[mf][2], rs[mf][3]};
      *(f32x4*)(base + mf * 16 + lh * 4) = v;
    }
  }
}

// ---------------------------------------------------------------------------
// Kernel 3: per-row denominators (coalesced partial reduction).
// ---------------------------------------------------------------------------
__global__ __launch_bounds__(256) void denom_kernel(
    const float* __restrict__ Rp, const float* __restrict__ R21p,
    float* __restrict__ dlog) {
  const int i = blockIdx.x * 256 + threadIdx.x;
  const float E2 = 7.3890560989306495f;
  float r11 = 0.f, r22 = 0.f, r12 = 0.f, r21 = 0.f;
#pragma unroll
  for (int k = 0; k < 8; ++k) r11 += Rp[(size_t)k * NROWS + i];
#pragma unroll
  for (int k = 8; k < 16; ++k) r22 += Rp[(size_t)k * NROWS + i];
#pragma unroll
  for (int k = 16; k < 24; ++k) r12 += Rp[(size_t)k * NROWS + i];
#pragma unroll
  for (int rb = 0; rb < 64; ++rb) r21 += R21p[(size_t)rb * NROWS + i];
  dlog[i] = 0.5f * (logf(r11 + r12 - E2) + logf(r22 + r21 - E2));
}

// ---------------------------------------------------------------------------
// Kernel 4: diag dots + per-row loss + block partials (deterministic).
// loss_i = -ln2 * dot_i + dlog[i]
// ---------------------------------------------------------------------------
__global__ __launch_bounds__(256) void loss_kernel(
    const unsigned short* __restrict__ hs1, const unsigned short* __restrict__ hs2,
    const float* __restrict__ dlog, float* __restrict__ partial) {
  const int tid = threadIdx.x;
  const int l = tid & 63;
  const int wv = tid >> 6;
  const int gw = blockIdx.x * 4 + wv;  // 0..1023
  const float LN2 = 0.6931471805599453f;
  float acc = 0.f;
  for (int t = 0; t < 8; ++t) {
    int i = gw * 8 + t;
    int off = (((l << 2) & ~15) ^ ((i & 7) << 4)) | ((l & 3) << 2);
    unsigned int a = *(const unsigned int*)((const char*)hs1 + (size_t)i * 256 + off);
    unsigned int b = *(const unsigned int*)((const char*)hs2 + (size_t)i * 256 + off);
    float p = bf2f(a & 0xffffu) * bf2f(b & 0xffffu) + bf2f(a >> 16) * bf2f(b >> 16);
#pragma unroll
    for (int m = 1; m < 64; m <<= 1) p += __shfl_xor(p, m, 64);
    if (l == 0) acc += -LN2 * p + dlog[i];
  }
  __shared__ float wacc[4];
  if (l == 0) wacc[wv] = acc;
  __syncthreads();
  if (tid == 0) partial[blockIdx.x] = wacc[0] + wacc[1] + wacc[2] + wacc[3];
}

__global__ void loss_final(const float* __restrict__ partial, float* __restrict__ outp) {
  const int t = threadIdx.x;
  float v = partial[t] + partial[t + 64] + partial[t + 128] + partial[t + 192];
#pragma unroll
  for (int m = 1; m < 64; m <<= 1) v += __shfl_xor(v, m, 64);
  if (t == 0) outp[0] = v * (1.0f / 8192.0f);
}

// ---------------------------------------------------------------------------
extern "C" void kernel_launch(void* const* d_in, const int* in_sizes, int n_in,
                              void* d_out, int out_size, void* d_ws, size_t ws_size,
                              hipStream_t stream) {
  const float* z1 = (const float*)d_in[0];
  const float* z2 = (const float*)d_in[1];
  const float* w1 = (const float*)d_in[2];
  const float* b1 = (const float*)d_in[3];
  const float* w2 = (const float*)d_in[4];
  const float* b2 = (const float*)d_in[5];
  char* ws = (char*)d_ws;
  unsigned short* hs1 = (unsigned short*)ws;                              // 0..2 MB
  unsigned short* hs2 = (unsigned short*)(ws + (size_t)2 * 1024 * 1024);  // 2..4 MB
  float* Rp = (float*)(ws + (size_t)4 * 1024 * 1024);                     // 24*8192*4 = 768 KB
  float* R21p = (float*)(ws + (size_t)4 * 1024 * 1024 + 768 * 1024);      // 64*8192*4 = 2 MB
  float* dlog = (float*)(ws + (size_t)7 * 1024 * 1024);                   // 32 KB
  float* partial = (float*)(ws + (size_t)7 * 1024 * 1024 + 64 * 1024);    // 1 KB
  float* outp = (float*)d_out;

  proj_kernel<<<dim3(256), dim3(256), 0, stream>>>(z1, z2, w1, b1, w2, b2, hs1, hs2);
  gram_kernel<<<dim3(1536), dim3(256), 0, stream>>>(hs1, hs2, Rp, R21p);
  denom_kernel<<<dim3(32), dim3(256), 0, stream>>>(Rp, R21p, dlog);
  loss_kernel<<<dim3(256), dim3(256), 0, stream>>>(hs1, hs2, dlog, partial);
  loss_final<<<dim3(1), dim3(64), 0, stream>>>(partial, outp);
}

// Round 14
// 84.208 us; speedup vs baseline: 1.4236x; 1.4236x over previous
//
#include <hip/hip_runtime.h>
#include <stdint.h>

typedef __attribute__((ext_vector_type(4))) float f32x4;
typedef __attribute__((ext_vector_type(8))) short short8;

#define NROWS 8192

static __device__ __forceinline__ unsigned int f2bf(float f) {
  unsigned int u = __float_as_uint(f);
  return (u + 0x7fffu + ((u >> 16) & 1u)) >> 16;  // RNE
}
static __device__ __forceinline__ float bf2f(unsigned int h) {
  return __uint_as_float(h << 16);
}
static __device__ __forceinline__ float fast_exp2(float x) {
  // args bounded: raw v_exp_f32, skip OCML range/denorm handling
#if __has_builtin(__builtin_amdgcn_exp2f)
  return __builtin_amdgcn_exp2f(x);
#else
  float r;
  asm("v_exp_f32 %0, %1" : "=v"(r) : "v"(x));
  return r;
#endif
}
static __device__ __forceinline__ float fast_expm1(float x) {
  // x <= ~4 in magnitude here; e^x - 1 via v_exp (OCML expm1f is multi-instr)
  return fast_exp2(x * 1.4426950408889634f) - 1.0f;
}

// hs layout: per 256B row r, 16B chunk c stored at chunk position c ^ (r&7).
// Linear global->LDS DMA then yields the bank-conflict-free swizzled LDS
// layout for ds_read_b128 fragments (G4 / m201 pre-swizzled-source pattern).

// ---------------------------------------------------------------------------
// Kernel 1: projection fc2(elu(fc1(z))) + L2-normalize, bf16 MFMA + f32
// epilogue. 256 blocks x 256 threads; block = 64 rows of one z. Output rows
// pre-scaled by sqrt(2*log2 e) so Gram MFMA output is the exp2 argument,
// written in the swizzled global layout. (r14: expm1f -> fast_expm1)
// ---------------------------------------------------------------------------
__global__ __launch_bounds__(256) void proj_kernel(
    const float* __restrict__ z1, const float* __restrict__ z2,
    const float* __restrict__ w1g, const float* __restrict__ b1g,
    const float* __restrict__ w2g, const float* __restrict__ b2g,
    unsigned short* __restrict__ hs1, unsigned short* __restrict__ hs2) {
  __shared__ unsigned short W1[128 * 128];
  __shared__ unsigned short W2[128 * 128];
  __shared__ unsigned short X[64 * 128];
  const int tid = threadIdx.x;
  const int w = tid >> 6, l = tid & 63, l16 = l & 15, lh = l >> 4;
  const int zi = blockIdx.x >> 7, rb = blockIdx.x & 127;
  const float* zg = (zi ? z2 : z1) + (size_t)rb * 64 * 128;
  unsigned short* outp = (zi ? hs2 : hs1) + (size_t)rb * 64 * 128;

  float bias1[8], bias2[8];
#pragma unroll
  for (int nf = 0; nf < 8; ++nf) {
    bias1[nf] = b1g[nf * 16 + l16];
    bias2[nf] = b2g[nf * 16 + l16];
  }

#pragma unroll
  for (int t = 0; t < 16; ++t) {
    int c = tid + t * 256;
    int r = c >> 5, q = c & 31;
    int off = r * 256 + ((((q >> 1) ^ (r & 7)) << 4) | ((q & 1) << 3));
    f32x4 va = *(const f32x4*)&w1g[c * 4];
    f32x4 vb = *(const f32x4*)&w2g[c * 4];
    uint2 pa, pb;
    pa.x = f2bf(va.x) | (f2bf(va.y) << 16);
    pa.y = f2bf(va.z) | (f2bf(va.w) << 16);
    pb.x = f2bf(vb.x) | (f2bf(vb.y) << 16);
    pb.y = f2bf(vb.z) | (f2bf(vb.w) << 16);
    *(uint2*)((char*)W1 + off) = pa;
    *(uint2*)((char*)W2 + off) = pb;
  }
#pragma unroll
  for (int t = 0; t < 8; ++t) {
    int c = tid + t * 256;
    int r = c >> 5, q = c & 31;
    int off = r * 256 + ((((q >> 1) ^ (r & 7)) << 4) | ((q & 1) << 3));
    f32x4 v = *(const f32x4*)&zg[c * 4];
    uint2 p;
    p.x = f2bf(v.x) | (f2bf(v.y) << 16);
    p.y = f2bf(v.z) | (f2bf(v.w) << 16);
    *(uint2*)((char*)X + off) = p;
  }
  __syncthreads();

  const f32x4 ZERO = {0.f, 0.f, 0.f, 0.f};
  const int arow = w * 16 + l16;

  short8 a1[4];
#pragma unroll
  for (int ks = 0; ks < 4; ++ks)
    a1[ks] = *(const short8*)((const char*)X + arow * 256 +
                              ((ks * 64 + lh * 16) ^ ((arow & 7) << 4)));
  f32x4 h[8];
#pragma unroll
  for (int nf = 0; nf < 8; ++nf) {
    const int brow = nf * 16 + l16;
    const char* bp = (const char*)W1 + brow * 256;
    f32x4 c = ZERO;
#pragma unroll
    for (int ks = 0; ks < 4; ++ks) {
      short8 b = *(const short8*)(bp + ((ks * 64 + lh * 16) ^ ((brow & 7) << 4)));
      c = __builtin_amdgcn_mfma_f32_16x16x32_bf16(a1[ks], b, c, 0, 0, 0);
    }
#pragma unroll
    for (int r = 0; r < 4; ++r) {
      float x = c[r] + bias1[nf];
      c[r] = x > 0.f ? x : fast_expm1(x);
    }
    h[nf] = c;
  }
  __syncthreads();

#pragma unroll
  for (int nf = 0; nf < 8; ++nf)
#pragma unroll
    for (int r = 0; r < 4; ++r) {
      int row = w * 16 + lh * 4 + r;
      int c2 = (nf * 16 + l16) * 2;
      int off = row * 256 + ((c2 & ~15) ^ ((row & 7) << 4)) + (c2 & 15);
      *(unsigned short*)((char*)X + off) = (unsigned short)f2bf(h[nf][r]);
    }
  __syncthreads();

  short8 a2[4];
#pragma unroll
  for (int ks = 0; ks < 4; ++ks)
    a2[ks] = *(const short8*)((const char*)X + arow * 256 +
                              ((ks * 64 + lh * 16) ^ ((arow & 7) << 4)));
  f32x4 o[8];
#pragma unroll
  for (int nf = 0; nf < 8; ++nf) {
    const int brow = nf * 16 + l16;
    const char* bp = (const char*)W2 + brow * 256;
    f32x4 c = ZERO;
#pragma unroll
    for (int ks = 0; ks < 4; ++ks) {
      short8 b = *(const short8*)(bp + ((ks * 64 + lh * 16) ^ ((brow & 7) << 4)));
      c = __builtin_amdgcn_mfma_f32_16x16x32_bf16(a2[ks], b, c, 0, 0, 0);
    }
#pragma unroll
    for (int r = 0; r < 4; ++r) c[r] += bias2[nf];
    o[nf] = c;
  }

  float ss[4] = {0.f, 0.f, 0.f, 0.f};
#pragma unroll
  for (int nf = 0; nf < 8; ++nf)
#pragma unroll
    for (int r = 0; r < 4; ++r) ss[r] += o[nf][r] * o[nf][r];
#pragma unroll
  for (int m = 1; m <= 8; m <<= 1)
#pragma unroll
    for (int r = 0; r < 4; ++r) ss[r] += __shfl_xor(ss[r], m, 64);
  float sc[4];
#pragma unroll
  for (int r = 0; r < 4; ++r)
    sc[r] = 1.6986436005760381f / fmaxf(sqrtf(ss[r]), 1e-12f);

#pragma unroll
  for (int nf = 0; nf < 8; ++nf)
#pragma unroll
    for (int r = 0; r < 4; ++r) {
      int row = w * 16 + lh * 4 + r;
      int c2 = (nf * 16 + l16) * 2;
      int off = row * 256 + ((c2 & ~15) ^ ((row & 7) << 4)) + (c2 & 15);
      *(unsigned short*)((char*)outp + off) = (unsigned short)f2bf(o[nf][r] * sc[r]);
    }
}

// ---------------------------------------------------------------------------
// Kernel 2: fused Gram + exp2 + row-sum (+ col-sum in pass 2). REVERTED to
// the round-9 structure verbatim (best measured: ~70us; r10-r13 variants all
// null or worse). 3 passes: 0 -> R11, 1 -> R22, 2 -> z1 x z2 (R12 + R21).
// Grid 768 = 3 x 32 rowblocks(256) x 8 col-ranges(1024), 256 threads,
// __launch_bounds__(256,3) (cap 170; caps <=128 spill af — r2/r5/r7).
// Deferred-exp pipeline + setprio; Bbuf[2] + __syncthreads per ct.
// ---------------------------------------------------------------------------
#define EXPBLOCK(G, SLOT)                                             \
  {                                                                   \
    float cs = 0.f;                                                   \
    _Pragma("unroll") for (int mf = 0; mf < 4; ++mf)                  \
        _Pragma("unroll") for (int r = 0; r < 4; ++r) {               \
      float e = fast_exp2(cbuf[SLOT][mf][r]);                         \
      rs[mf][r] += e;                                                 \
      if (do_cs) cs += e;                                             \
    }                                                                 \
    if (do_cs) {                                                      \
      cs += __shfl_xor(cs, 16, 64);                                   \
      cs += __shfl_xor(cs, 32, 64);                                   \
      if (lh == 0) csbuf[cur][w][(G)*16 + l16] = cs;                  \
    }                                                                 \
  }

__global__ __launch_bounds__(256, 3) void gram_kernel(
    const unsigned short* __restrict__ hs1, const unsigned short* __restrict__ hs2,
    float* __restrict__ Rp,     // [24][8192] (pass*8+cr) row-sum partials
    float* __restrict__ R21p) { // [32][8192] col-sum partials (pass 2)
  __shared__ unsigned short Bbuf[2][64 * 128];
  __shared__ float csbuf[2][4][64];

  const int tid = threadIdx.x;
  const int w = tid >> 6, l = tid & 63, l16 = l & 15, lh = l >> 4;
  const int pass = blockIdx.x >> 8;
  const int idx = blockIdx.x & 255;
  const int rb = idx >> 3;  // 32 rowblocks of 256 rows
  const int cr = idx & 7;   // 8 col-ranges of 1024 cols

  const unsigned short* Ag = (pass == 1) ? hs2 : hs1;
  const unsigned short* Bg = (pass == 0) ? hs1 : hs2;
  const char* bbase = (const char*)Bg + (size_t)cr * (1024 * 256);
  const bool do_cs = (pass == 2);

  auto STAGE = [&](int buf, int ct) {
#pragma unroll
    for (int s = 0; s < 4; ++s) {
      const char* src = bbase + (size_t)ct * 16384 + s * 4096 + tid * 16;
      char* dst = (char*)Bbuf[buf] + s * 4096 + w * 1024;  // wave-uniform base
      __builtin_amdgcn_global_load_lds(
          (const __attribute__((address_space(1))) void*)src,
          (__attribute__((address_space(3))) void*)dst, 16, 0, 0);
    }
  };

  STAGE(0, 0);

  short8 af[4][4];  // 64 rows per wave, resident (64 VGPRs)
  {
    const char* abase = (const char*)Ag + ((size_t)rb * 256 + w * 64) * 256;
#pragma unroll
    for (int mf = 0; mf < 4; ++mf) {
      int row = mf * 16 + l16;
#pragma unroll
      for (int ks = 0; ks < 4; ++ks)
        af[mf][ks] = *(const short8*)(abase + row * 256 +
                                      ((ks * 64 + lh * 16) ^ ((row & 7) << 4)));
    }
  }

  float rs[4][4];
#pragma unroll
  for (int mf = 0; mf < 4; ++mf)
#pragma unroll
    for (int r = 0; r < 4; ++r) rs[mf][r] = 0.f;
  const f32x4 ZERO = {0.f, 0.f, 0.f, 0.f};

  __syncthreads();  // tile 0 staged

  for (int ct = 0; ct < 16; ++ct) {
    const int cur = ct & 1;
    if (ct + 1 < 16) STAGE(cur ^ 1, ct + 1);
    if (do_cs && w == 0 && ct > 0) {  // flush prev tile's col-sums (overlaps)
      float v = (csbuf[cur ^ 1][0][l] + csbuf[cur ^ 1][1][l]) +
                (csbuf[cur ^ 1][2][l] + csbuf[cur ^ 1][3][l]);
      R21p[(size_t)rb * NROWS + cr * 1024 + (ct - 1) * 64 + l] = v;
    }
    f32x4 cbuf[2][4];
#pragma unroll
    for (int nf = 0; nf < 4; ++nf) {
      short8 bf[4];
      const int brow = nf * 16 + l16;
      const char* bp = (const char*)Bbuf[cur] + brow * 256;
#pragma unroll
      for (int ks = 0; ks < 4; ++ks)
        bf[ks] = *(const short8*)(bp + ((ks * 64 + lh * 16) ^ ((brow & 7) << 4)));
#pragma unroll
      for (int mf = 0; mf < 4; ++mf) cbuf[nf & 1][mf] = ZERO;
      __builtin_amdgcn_s_setprio(1);
#pragma unroll
      for (int ks = 0; ks < 4; ++ks)  // ks-outer: 4 independent acc chains
#pragma unroll
        for (int mf = 0; mf < 4; ++mf)
          cbuf[nf & 1][mf] = __builtin_amdgcn_mfma_f32_16x16x32_bf16(
              af[mf][ks], bf[ks], cbuf[nf & 1][mf], 0, 0, 0);
      __builtin_amdgcn_s_setprio(0);
      // deferred exp: process PREVIOUS group's C (operands long ready)
      if (nf > 0) EXPBLOCK(nf - 1, (nf ^ 1) & 1);
    }
    EXPBLOCK(3, 1);  // last group's exp
    __syncthreads();
  }
  if (do_cs && w == 0) {  // flush last tile (ct=15 -> buf 1)
    float v = (csbuf[1][0][l] + csbuf[1][1][l]) + (csbuf[1][2][l] + csbuf[1][3][l]);
    R21p[(size_t)rb * NROWS + cr * 1024 + 15 * 64 + l] = v;
  }

  // row-sums: reduce over the 16 col-lanes; A-row = mf*16 + lh*4 + r [m89]
#pragma unroll
  for (int m = 1; m <= 8; m <<= 1)
#pragma unroll
    for (int mf = 0; mf < 4; ++mf)
#pragma unroll
      for (int r = 0; r < 4; ++r) rs[mf][r] += __shfl_xor(rs[mf][r], m, 64);
  if (l16 == 0) {
    float* base = &Rp[(size_t)(pass * 8 + cr) * NROWS + rb * 256 + w * 64];
#pragma unroll
    for (int mf = 0; mf < 4; ++mf) {
      f32x4 v = {rs[mf][0], rs[mf][1], rs[mf][2], rs[mf][3]};
      *(f32x4*)(base + mf * 16 + lh * 4) = v;
    }
  }
}

// ---------------------------------------------------------------------------
// Kernel 3 (r14: MERGED denom+loss): per-row loss with lane-parallel
// denominator gather. Lane k<24 loads Rp[k][i] (r11:0-7, r22:8-15,
// r12:16-23); lanes 24..55 load R21p[k-24][i]. Two masked wave-reduces give
// d1 = r11+r12, d2 = r22+r21. Removes the latency-bound 32-block denom
// kernel + dlog roundtrip. loss_i = -ln2*dot_i + 0.5*(log(d1-e2)+log(d2-e2)).
// ---------------------------------------------------------------------------
__global__ __launch_bounds__(256) void loss_kernel(
    const unsigned short* __restrict__ hs1, const unsigned short* __restrict__ hs2,
    const float* __restrict__ Rp, const float* __restrict__ R21p,
    float* __restrict__ partial) {
  const int tid = threadIdx.x;
  const int l = tid & 63;
  const int wv = tid >> 6;
  const int gw = blockIdx.x * 4 + wv;  // 0..1023
  const float E2 = 7.3890560989306495f;
  const float LN2 = 0.6931471805599453f;
  const bool in1 = (l < 8) | ((l >= 16) & (l < 24));   // r11 | r12 lanes
  const bool in2 = ((l >= 8) & (l < 16)) | ((l >= 24) & (l < 56));
  float acc = 0.f;
  for (int t = 0; t < 8; ++t) {
    int i = gw * 8 + t;
    // diag dot of the alpha-scaled rows (dot = 2*log2e*s -> -2s = -ln2*dot)
    int off = (((l << 2) & ~15) ^ ((i & 7) << 4)) | ((l & 3) << 2);
    unsigned int a = *(const unsigned int*)((const char*)hs1 + (size_t)i * 256 + off);
    unsigned int b = *(const unsigned int*)((const char*)hs2 + (size_t)i * 256 + off);
    float p = bf2f(a & 0xffffu) * bf2f(b & 0xffffu) + bf2f(a >> 16) * bf2f(b >> 16);
    // lane-parallel denominator partials
    float v = 0.f;
    if (l < 24)
      v = Rp[(size_t)l * NROWS + i];
    else if (l < 56)
      v = R21p[(size_t)(l - 24) * NROWS + i];
    float v1 = in1 ? v : 0.f;
    float v2 = in2 ? v : 0.f;
#pragma unroll
    for (int m = 1; m < 64; m <<= 1) {
      p += __shfl_xor(p, m, 64);
      v1 += __shfl_xor(v1, m, 64);
      v2 += __shfl_xor(v2, m, 64);
    }
    if (l == 0)
      acc += -LN2 * p + 0.5f * (logf(v1 - E2) + logf(v2 - E2));
  }
  __shared__ float wacc[4];
  if (l == 0) wacc[wv] = acc;
  __syncthreads();
  if (tid == 0) partial[blockIdx.x] = wacc[0] + wacc[1] + wacc[2] + wacc[3];
}

__global__ void loss_final(const float* __restrict__ partial, float* __restrict__ outp) {
  const int t = threadIdx.x;
  float v = partial[t] + partial[t + 64] + partial[t + 128] + partial[t + 192];
#pragma unroll
  for (int m = 1; m < 64; m <<= 1) v += __shfl_xor(v, m, 64);
  if (t == 0) outp[0] = v * (1.0f / 8192.0f);
}

// ---------------------------------------------------------------------------
extern "C" void kernel_launch(void* const* d_in, const int* in_sizes, int n_in,
                              void* d_out, int out_size, void* d_ws, size_t ws_size,
                              hipStream_t stream) {
  const float* z1 = (const float*)d_in[0];
  const float* z2 = (const float*)d_in[1];
  const float* w1 = (const float*)d_in[2];
  const float* b1 = (const float*)d_in[3];
  const float* w2 = (const float*)d_in[4];
  const float* b2 = (const float*)d_in[5];
  char* ws = (char*)d_ws;
  unsigned short* hs1 = (unsigned short*)ws;                              // 0..2 MB
  unsigned short* hs2 = (unsigned short*)(ws + (size_t)2 * 1024 * 1024);  // 2..4 MB
  float* Rp = (float*)(ws + (size_t)4 * 1024 * 1024);                     // 24*8192*4 = 768 KB
  float* R21p = (float*)(ws + (size_t)4 * 1024 * 1024 + 768 * 1024);      // 32*8192*4 = 1 MB
  float* partial = (float*)(ws + (size_t)6 * 1024 * 1024);                // 1 KB
  float* outp = (float*)d_out;

  proj_kernel<<<dim3(256), dim3(256), 0, stream>>>(z1, z2, w1, b1, w2, b2, hs1, hs2);
  gram_kernel<<<dim3(768), dim3(256), 0, stream>>>(hs1, hs2, Rp, R21p);
  loss_kernel<<<dim3(256), dim3(256), 0, stream>>>(hs1, hs2, Rp, R21p, partial);
  loss_final<<<dim3(1), dim3(64), 0, stream>>>(partial, outp);
}

// Round 15
// 61.218 us; speedup vs baseline: 1.9583x; 1.3755x over previous
//
#include <hip/hip_runtime.h>
#include <stdint.h>

typedef __attribute__((ext_vector_type(4))) float f32x4;
typedef __attribute__((ext_vector_type(8))) short short8;
typedef __attribute__((ext_vector_type(8))) int int8v;

#define NROWS 8192
#define SCALE1 0x7F7F7F7F  // 4x E8M0 bytes encoding 2^0 = 1.0

static __device__ __forceinline__ unsigned int f2bf(float f) {
  unsigned int u = __float_as_uint(f);
  return (u + 0x7fffu + ((u >> 16) & 1u)) >> 16;  // RNE
}
static __device__ __forceinline__ float bf2f(unsigned int h) {
  return __uint_as_float(h << 16);
}
static __device__ __forceinline__ float fast_exp2(float x) {
#if __has_builtin(__builtin_amdgcn_exp2f)
  return __builtin_amdgcn_exp2f(x);
#else
  float r;
  asm("v_exp_f32 %0, %1" : "=v"(r) : "v"(x));
  return r;
#endif
}
static __device__ __forceinline__ float fast_expm1(float x) {
  return fast_exp2(x * 1.4426950408889634f) - 1.0f;
}
// f32 -> OCP e4m3fn byte
static __device__ __forceinline__ unsigned f2fp8(float v) {
#if __has_builtin(__builtin_amdgcn_cvt_pk_fp8_f32)
  return (unsigned)__builtin_amdgcn_cvt_pk_fp8_f32(v, v, 0, false) & 0xFFu;
#else
  float a = fabsf(v);
  unsigned sgn = v < 0.f ? 0x80u : 0u;
  if (a > 448.f) a = 448.f;
  if (a < 0.015625f) {  // subnormal: units of 2^-9 (q==8 -> e=1,m=0 = enc 8)
    int q = (int)(a * 512.0f + 0.5f);
    return sgn | (unsigned)q;
  }
  int ex;
  float mant = frexpf(a, &ex);  // a = mant*2^ex, mant in [0.5,1)
  int e = ex + 6;
  int m = (int)(mant * 16.0f + 0.5f) - 8;
  if (m == 8) { m = 0; ++e; }
  if (e > 15) { e = 15; m = 7; }
  return sgn | (unsigned)(e << 3) | (unsigned)m;
#endif
}
// OCP e4m3fn byte -> f32
static __device__ __forceinline__ float fp8d(unsigned b) {
  unsigned e = (b >> 3) & 15u, m = b & 7u;
  float v = (e == 0) ? (float)m * 0.001953125f
                     : __uint_as_float(((e + 120u) << 23) | (m << 20));
  return (b & 0x80u) ? -v : v;
}

// hs-fp8 layout: rows of 128 B; 16B chunk c stored at position c ^ (row&7).
// Pre-swizzled global + linear global_load_lds DMA + per-lane swizzled read
// addresses (m201 both-sides pattern). Lane fragment for 16x16x128 MFMA:
// row = l&15, k-bytes [32*(l>>4), 32*(l>>4)+32) = logical chunks {2lh, 2lh+1}.

// ---------------------------------------------------------------------------
// Kernel 1: projection fc2(elu(fc1(z))) + L2-normalize, bf16 MFMA + f32
// epilogue. Internals unchanged (bf16 in LDS); FINAL output now fp8 e4m3
// rows pre-scaled by sqrt(2*log2 e) so the scaled-MFMA Gram output is the
// exp2 argument directly. 256 blocks x 256 threads; block = 64 rows.
// ---------------------------------------------------------------------------
__global__ __launch_bounds__(256) void proj_kernel(
    const float* __restrict__ z1, const float* __restrict__ z2,
    const float* __restrict__ w1g, const float* __restrict__ b1g,
    const float* __restrict__ w2g, const float* __restrict__ b2g,
    unsigned char* __restrict__ hs1, unsigned char* __restrict__ hs2) {
  __shared__ unsigned short W1[128 * 128];
  __shared__ unsigned short W2[128 * 128];
  __shared__ unsigned short X[64 * 128];
  const int tid = threadIdx.x;
  const int w = tid >> 6, l = tid & 63, l16 = l & 15, lh = l >> 4;
  const int zi = blockIdx.x >> 7, rb = blockIdx.x & 127;
  const float* zg = (zi ? z2 : z1) + (size_t)rb * 64 * 128;
  unsigned char* outp = (zi ? hs2 : hs1) + (size_t)rb * 64 * 128;

  float bias1[8], bias2[8];
#pragma unroll
  for (int nf = 0; nf < 8; ++nf) {
    bias1[nf] = b1g[nf * 16 + l16];
    bias2[nf] = b2g[nf * 16 + l16];
  }

#pragma unroll
  for (int t = 0; t < 16; ++t) {
    int c = tid + t * 256;
    int r = c >> 5, q = c & 31;
    int off = r * 256 + ((((q >> 1) ^ (r & 7)) << 4) | ((q & 1) << 3));
    f32x4 va = *(const f32x4*)&w1g[c * 4];
    f32x4 vb = *(const f32x4*)&w2g[c * 4];
    uint2 pa, pb;
    pa.x = f2bf(va.x) | (f2bf(va.y) << 16);
    pa.y = f2bf(va.z) | (f2bf(va.w) << 16);
    pb.x = f2bf(vb.x) | (f2bf(vb.y) << 16);
    pb.y = f2bf(vb.z) | (f2bf(vb.w) << 16);
    *(uint2*)((char*)W1 + off) = pa;
    *(uint2*)((char*)W2 + off) = pb;
  }
#pragma unroll
  for (int t = 0; t < 8; ++t) {
    int c = tid + t * 256;
    int r = c >> 5, q = c & 31;
    int off = r * 256 + ((((q >> 1) ^ (r & 7)) << 4) | ((q & 1) << 3));
    f32x4 v = *(const f32x4*)&zg[c * 4];
    uint2 p;
    p.x = f2bf(v.x) | (f2bf(v.y) << 16);
    p.y = f2bf(v.z) | (f2bf(v.w) << 16);
    *(uint2*)((char*)X + off) = p;
  }
  __syncthreads();

  const f32x4 ZERO = {0.f, 0.f, 0.f, 0.f};
  const int arow = w * 16 + l16;

  short8 a1[4];
#pragma unroll
  for (int ks = 0; ks < 4; ++ks)
    a1[ks] = *(const short8*)((const char*)X + arow * 256 +
                              ((ks * 64 + lh * 16) ^ ((arow & 7) << 4)));
  f32x4 h[8];
#pragma unroll
  for (int nf = 0; nf < 8; ++nf) {
    const int brow = nf * 16 + l16;
    const char* bp = (const char*)W1 + brow * 256;
    f32x4 c = ZERO;
#pragma unroll
    for (int ks = 0; ks < 4; ++ks) {
      short8 b = *(const short8*)(bp + ((ks * 64 + lh * 16) ^ ((brow & 7) << 4)));
      c = __builtin_amdgcn_mfma_f32_16x16x32_bf16(a1[ks], b, c, 0, 0, 0);
    }
#pragma unroll
    for (int r = 0; r < 4; ++r) {
      float x = c[r] + bias1[nf];
      c[r] = x > 0.f ? x : fast_expm1(x);
    }
    h[nf] = c;
  }
  __syncthreads();

#pragma unroll
  for (int nf = 0; nf < 8; ++nf)
#pragma unroll
    for (int r = 0; r < 4; ++r) {
      int row = w * 16 + lh * 4 + r;
      int c2 = (nf * 16 + l16) * 2;
      int off = row * 256 + ((c2 & ~15) ^ ((row & 7) << 4)) + (c2 & 15);
      *(unsigned short*)((char*)X + off) = (unsigned short)f2bf(h[nf][r]);
    }
  __syncthreads();

  short8 a2[4];
#pragma unroll
  for (int ks = 0; ks < 4; ++ks)
    a2[ks] = *(const short8*)((const char*)X + arow * 256 +
                              ((ks * 64 + lh * 16) ^ ((arow & 7) << 4)));
  f32x4 o[8];
#pragma unroll
  for (int nf = 0; nf < 8; ++nf) {
    const int brow = nf * 16 + l16;
    const char* bp = (const char*)W2 + brow * 256;
    f32x4 c = ZERO;
#pragma unroll
    for (int ks = 0; ks < 4; ++ks) {
      short8 b = *(const short8*)(bp + ((ks * 64 + lh * 16) ^ ((brow & 7) << 4)));
      c = __builtin_amdgcn_mfma_f32_16x16x32_bf16(a2[ks], b, c, 0, 0, 0);
    }
#pragma unroll
    for (int r = 0; r < 4; ++r) c[r] += bias2[nf];
    o[nf] = c;
  }

  float ss[4] = {0.f, 0.f, 0.f, 0.f};
#pragma unroll
  for (int nf = 0; nf < 8; ++nf)
#pragma unroll
    for (int r = 0; r < 4; ++r) ss[r] += o[nf][r] * o[nf][r];
#pragma unroll
  for (int m = 1; m <= 8; m <<= 1)
#pragma unroll
    for (int r = 0; r < 4; ++r) ss[r] += __shfl_xor(ss[r], m, 64);
  float sc[4];
#pragma unroll
  for (int r = 0; r < 4; ++r)
    sc[r] = 1.6986436005760381f / fmaxf(sqrtf(ss[r]), 1e-12f);

  // fp8 store: logical byte = row*128 + col, col = nf*16+l16 -> chunk = nf;
  // phys = row*128 + ((nf ^ (row&7))<<4) + l16
#pragma unroll
  for (int nf = 0; nf < 8; ++nf)
#pragma unroll
    for (int r = 0; r < 4; ++r) {
      int row = w * 16 + lh * 4 + r;
      outp[(size_t)row * 128 + ((nf ^ (row & 7)) << 4) + l16] =
          (unsigned char)f2fp8(o[nf][r] * sc[r]);
    }
}

// ---------------------------------------------------------------------------
// Kernel 2: fused Gram + exp2 + row-sum (+ col-sum in pass 2), FP8-MX.
// ROUND-15 CHANGE: hs stored as fp8 e4m3 (rows 128B, chunk-swizzled); the
// ENTIRE K=128 dot is ONE mfma_scale_f32_16x16x128_f8f6f4 (scales = 1.0,
// 2.25x bf16 MFMA rate per m148). LDS/DMA/af all halve. Shell = r9 proven:
// grid 768 = 3 x 32 rowblocks(256) x 8 col-ranges(1024), 256 thr,
// __launch_bounds__(256,3), deferred-exp + setprio, Bbuf[2] + syncthreads.
// ---------------------------------------------------------------------------
#define EXPBLOCK(G, SLOT)                                             \
  {                                                                   \
    float cs = 0.f;                                                   \
    _Pragma("unroll") for (int mf = 0; mf < 4; ++mf)                  \
        _Pragma("unroll") for (int r = 0; r < 4; ++r) {               \
      float e = fast_exp2(cbuf[SLOT][mf][r]);                         \
      rs[mf][r] += e;                                                 \
      if (do_cs) cs += e;                                             \
    }                                                                 \
    if (do_cs) {                                                      \
      cs += __shfl_xor(cs, 16, 64);                                   \
      cs += __shfl_xor(cs, 32, 64);                                   \
      if (lh == 0) csbuf[cur][w][(G)*16 + l16] = cs;                  \
    }                                                                 \
  }

__global__ __launch_bounds__(256, 3) void gram_kernel(
    const unsigned char* __restrict__ hs1, const unsigned char* __restrict__ hs2,
    float* __restrict__ Rp,     // [24][8192] (pass*8+cr) row-sum partials
    float* __restrict__ R21p) { // [32][8192] col-sum partials (pass 2)
  __shared__ __align__(16) unsigned char Bbuf[2][64 * 128];  // 2 x 8KB
  __shared__ float csbuf[2][4][64];

  const int tid = threadIdx.x;
  const int w = tid >> 6, l = tid & 63, l16 = l & 15, lh = l >> 4;
  const int pass = blockIdx.x >> 8;
  const int idx = blockIdx.x & 255;
  const int rb = idx >> 3;  // 32 rowblocks of 256 rows
  const int cr = idx & 7;   // 8 col-ranges of 1024 cols

  const unsigned char* Ag = (pass == 1) ? hs2 : hs1;
  const unsigned char* Bg = (pass == 0) ? hs1 : hs2;
  const char* bbase = (const char*)Bg + (size_t)cr * (1024 * 128);
  const bool do_cs = (pass == 2);

  auto STAGE = [&](int buf, int ct) {
#pragma unroll
    for (int s = 0; s < 2; ++s) {
      const char* src = bbase + (size_t)ct * 8192 + s * 4096 + tid * 16;
      char* dst = (char*)Bbuf[buf] + s * 4096 + w * 1024;  // wave-uniform base
      __builtin_amdgcn_global_load_lds(
          (const __attribute__((address_space(1))) void*)src,
          (__attribute__((address_space(3))) void*)dst, 16, 0, 0);
    }
  };

  STAGE(0, 0);

  // per-lane swizzled 16B-chunk offsets for the 2 halves of a 32B fragment
  const int koff0 = ((2 * lh) ^ (l16 & 7)) << 4;
  const int koff1 = ((2 * lh + 1) ^ (l16 & 7)) << 4;

  int8v af[4];  // 64 rows per wave: 4 x 8 VGPRs = 32 VGPRs
  {
    const char* abase = (const char*)Ag + ((size_t)rb * 256 + w * 64) * 128;
#pragma unroll
    for (int mf = 0; mf < 4; ++mf) {
      const char* rp = abase + (mf * 16 + l16) * 128;
      int4 x0 = *(const int4*)(rp + koff0);
      int4 x1 = *(const int4*)(rp + koff1);
      int8v v;
      v[0] = x0.x; v[1] = x0.y; v[2] = x0.z; v[3] = x0.w;
      v[4] = x1.x; v[5] = x1.y; v[6] = x1.z; v[7] = x1.w;
      af[mf] = v;
    }
  }

  float rs[4][4];
#pragma unroll
  for (int mf = 0; mf < 4; ++mf)
#pragma unroll
    for (int r = 0; r < 4; ++r) rs[mf][r] = 0.f;
  const f32x4 ZERO = {0.f, 0.f, 0.f, 0.f};

  __syncthreads();  // tile 0 staged

  for (int ct = 0; ct < 16; ++ct) {
    const int cur = ct & 1;
    if (ct + 1 < 16) STAGE(cur ^ 1, ct + 1);
    if (do_cs && w == 0 && ct > 0) {  // flush prev tile's col-sums (overlaps)
      float v = (csbuf[cur ^ 1][0][l] + csbuf[cur ^ 1][1][l]) +
                (csbuf[cur ^ 1][2][l] + csbuf[cur ^ 1][3][l]);
      R21p[(size_t)rb * NROWS + cr * 1024 + (ct - 1) * 64 + l] = v;
    }
    f32x4 cbuf[2][4];
#pragma unroll
    for (int nf = 0; nf < 4; ++nf) {
      const char* bp = (const char*)Bbuf[cur] + (nf * 16 + l16) * 128;
      int4 b0 = *(const int4*)(bp + koff0);
      int4 b1 = *(const int4*)(bp + koff1);
      int8v bv;
      bv[0] = b0.x; bv[1] = b0.y; bv[2] = b0.z; bv[3] = b0.w;
      bv[4] = b1.x; bv[5] = b1.y; bv[6] = b1.z; bv[7] = b1.w;
      __builtin_amdgcn_s_setprio(1);
#pragma unroll
      for (int mf = 0; mf < 4; ++mf)  // one MFMA = full K=128 dot
        cbuf[nf & 1][mf] = __builtin_amdgcn_mfma_scale_f32_16x16x128_f8f6f4(
            af[mf], bv, ZERO, 0, 0, 0, SCALE1, 0, SCALE1);
      __builtin_amdgcn_s_setprio(0);
      // deferred exp: process PREVIOUS group's C (operands long ready)
      if (nf > 0) EXPBLOCK(nf - 1, (nf ^ 1) & 1);
    }
    EXPBLOCK(3, 1);  // last group's exp
    __syncthreads();
  }
  if (do_cs && w == 0) {  // flush last tile (ct=15 -> buf 1)
    float v = (csbuf[1][0][l] + csbuf[1][1][l]) + (csbuf[1][2][l] + csbuf[1][3][l]);
    R21p[(size_t)rb * NROWS + cr * 1024 + 15 * 64 + l] = v;
  }

  // row-sums: reduce over the 16 col-lanes; C/D row = mf*16 + lh*4 + r [m89]
#pragma unroll
  for (int m = 1; m <= 8; m <<= 1)
#pragma unroll
    for (int mf = 0; mf < 4; ++mf)
#pragma unroll
      for (int r = 0; r < 4; ++r) rs[mf][r] += __shfl_xor(rs[mf][r], m, 64);
  if (l16 == 0) {
    float* base = &Rp[(size_t)(pass * 8 + cr) * NROWS + rb * 256 + w * 64];
#pragma unroll
    for (int mf = 0; mf < 4; ++mf) {
      f32x4 v = {rs[mf][0], rs[mf][1], rs[mf][2], rs[mf][3]};
      *(f32x4*)(base + mf * 16 + lh * 4) = v;
    }
  }
}

// ---------------------------------------------------------------------------
// Kernel 3: merged denom+loss (r14 structure). Diag dot now decodes fp8:
// lane l reads logical bytes {2l, 2l+1} of row i (both in chunk l>>3).
// ---------------------------------------------------------------------------
__global__ __launch_bounds__(256) void loss_kernel(
    const unsigned char* __restrict__ hs1, const unsigned char* __restrict__ hs2,
    const float* __restrict__ Rp, const float* __restrict__ R21p,
    float* __restrict__ partial) {
  const int tid = threadIdx.x;
  const int l = tid & 63;
  const int wv = tid >> 6;
  const int gw = blockIdx.x * 4 + wv;  // 0..1023
  const float E2 = 7.3890560989306495f;
  const float LN2 = 0.6931471805599453f;
  const bool in1 = (l < 8) | ((l >= 16) & (l < 24));  // r11 | r12 lanes
  const bool in2 = ((l >= 8) & (l < 16)) | ((l >= 24) & (l < 56));
  float acc = 0.f;
  for (int t = 0; t < 8; ++t) {
    int i = gw * 8 + t;
    int off = (((l >> 3) ^ (i & 7)) << 4) + ((2 * l) & 15);
    unsigned int a = *(const unsigned short*)(hs1 + (size_t)i * 128 + off);
    unsigned int b = *(const unsigned short*)(hs2 + (size_t)i * 128 + off);
    float p = fp8d(a & 0xFFu) * fp8d(b & 0xFFu) + fp8d(a >> 8) * fp8d(b >> 8);
    float v = 0.f;
    if (l < 24)
      v = Rp[(size_t)l * NROWS + i];
    else if (l < 56)
      v = R21p[(size_t)(l - 24) * NROWS + i];
    float v1 = in1 ? v : 0.f;
    float v2 = in2 ? v : 0.f;
#pragma unroll
    for (int m = 1; m < 64; m <<= 1) {
      p += __shfl_xor(p, m, 64);
      v1 += __shfl_xor(v1, m, 64);
      v2 += __shfl_xor(v2, m, 64);
    }
    if (l == 0)
      acc += -LN2 * p + 0.5f * (logf(v1 - E2) + logf(v2 - E2));
  }
  __shared__ float wacc[4];
  if (l == 0) wacc[wv] = acc;
  __syncthreads();
  if (tid == 0) partial[blockIdx.x] = wacc[0] + wacc[1] + wacc[2] + wacc[3];
}

__global__ void loss_final(const float* __restrict__ partial, float* __restrict__ outp) {
  const int t = threadIdx.x;
  float v = partial[t] + partial[t + 64] + partial[t + 128] + partial[t + 192];
#pragma unroll
  for (int m = 1; m < 64; m <<= 1) v += __shfl_xor(v, m, 64);
  if (t == 0) outp[0] = v * (1.0f / 8192.0f);
}

// ---------------------------------------------------------------------------
extern "C" void kernel_launch(void* const* d_in, const int* in_sizes, int n_in,
                              void* d_out, int out_size, void* d_ws, size_t ws_size,
                              hipStream_t stream) {
  const float* z1 = (const float*)d_in[0];
  const float* z2 = (const float*)d_in[1];
  const float* w1 = (const float*)d_in[2];
  const float* b1 = (const float*)d_in[3];
  const float* w2 = (const float*)d_in[4];
  const float* b2 = (const float*)d_in[5];
  char* ws = (char*)d_ws;
  unsigned char* hs1 = (unsigned char*)ws;                               // 0..1 MB
  unsigned char* hs2 = (unsigned char*)(ws + (size_t)1 * 1024 * 1024);   // 1..2 MB
  float* Rp = (float*)(ws + (size_t)2 * 1024 * 1024);                    // 768 KB
  float* R21p = (float*)(ws + (size_t)2 * 1024 * 1024 + 768 * 1024);     // 1 MB
  float* partial = (float*)(ws + (size_t)4 * 1024 * 1024);               // 1 KB
  float* outp = (float*)d_out;

  proj_kernel<<<dim3(256), dim3(256), 0, stream>>>(z1, z2, w1, b1, w2, b2, hs1, hs2);
  gram_kernel<<<dim3(768), dim3(256), 0, stream>>>(hs1, hs2, Rp, R21p);
  loss_kernel<<<dim3(256), dim3(256), 0, stream>>>(hs1, hs2, Rp, R21p, partial);
  loss_final<<<dim3(1), dim3(64), 0, stream>>>(partial, outp);
}